// Round 1
// 2331.445 us; speedup vs baseline: 1.0259x; 1.0259x over previous
//
#include <hip/hip_runtime.h>

// Problem constants
#define SEQ   512
#define BATCH 64
#define IS    512
#define HS    512
#define G4    2048   // 4*HS

typedef _Float16 half8 __attribute__((ext_vector_type(8)));
typedef _Float16 half4 __attribute__((ext_vector_type(4)));
typedef float floatx4 __attribute__((ext_vector_type(4)));
typedef unsigned long long ull;

__device__ __forceinline__ float sigm(float x) {
    return 1.0f / (1.0f + __expf(-x));
}
__device__ __forceinline__ float tanh_(float x) {
    float e = __expf(-2.0f * fabsf(x));
    float r = (1.0f - e) / (1.0f + e);
    return copysignf(r, x);
}

// ---------------------------------------------------------------------------
// 1) fp32 -> f16 convert (x), vectorized 4-wide
// ---------------------------------------------------------------------------
__global__ void convert_f32_f16(const float* __restrict__ in,
                                _Float16* __restrict__ out, int n4) {
    int i = blockIdx.x * blockDim.x + threadIdx.x;
    if (i < n4) {
        float4 v = ((const float4*)in)[i];
        half4 o = { (_Float16)v.x, (_Float16)v.y, (_Float16)v.z, (_Float16)v.w };
        ((half4*)out)[i] = o;
    }
}

// ---------------------------------------------------------------------------
// 2) W [512][2048] fp32  ->  Wt [2048][512] f16  (k-contiguous for MFMA frags)
// ---------------------------------------------------------------------------
__global__ void transpose_w(const float* __restrict__ in, _Float16* __restrict__ out) {
    __shared__ _Float16 tile[64][72];   // +8 pad
    int bk = blockIdx.x & 7;            // k tile  (512/64)
    int bn = blockIdx.x >> 3;           // n tile  (2048/64)
    int c = threadIdx.x & 63;
    int r4 = threadIdx.x >> 6;          // 0..3
    #pragma unroll
    for (int rr = 0; rr < 16; rr++) {
        int k = rr * 4 + r4;
        tile[k][c] = (_Float16)in[(size_t)(bk * 64 + k) * 2048 + bn * 64 + c];
    }
    __syncthreads();
    #pragma unroll
    for (int rr = 0; rr < 16; rr++) {
        int n = rr * 4 + r4;
        out[(size_t)(bn * 64 + n) * 512 + bk * 64 + c] = tile[c][n];
    }
}

// ---------------------------------------------------------------------------
// 3) x_proj GEMM. Output layout (f16):  xp[t][wg][b][u][gate]
//    elem = ((t*32 + wg)*64 + b)*64 + u*4 + gate,  hid = wg*16+u
//    -> scan reads one half4 (4 gates) per (b,u), fully coalesced.
// ---------------------------------------------------------------------------
__global__ void __launch_bounds__(256, 2) gemm_xproj(
    const _Float16* __restrict__ A,
    const _Float16* __restrict__ Bt,
    _Float16* __restrict__ xp) {
    __shared__ _Float16 As[4096];   // 128 rows x 32 k
    __shared__ _Float16 Bs[4096];   // 128 n-rows x 32 k
    const int tid = threadIdx.x;
    const int w = tid >> 6, l = tid & 63, lr = l & 15, q = l >> 4;
    const int bm = blockIdx.x & 255, bn = blockIdx.x >> 8;
    const int row0 = bm * 128, col0 = bn * 128;
    const int wr = (w >> 1) * 64, wc = (w & 1) * 64;

    floatx4 zz = {0.f, 0.f, 0.f, 0.f};
    floatx4 acc[4][4];
    #pragma unroll
    for (int mt = 0; mt < 4; mt++)
        #pragma unroll
        for (int ct = 0; ct < 4; ct++) acc[mt][ct] = zz;

    for (int kt = 0; kt < 16; kt++) {
        __syncthreads();
        #pragma unroll
        for (int rnd = 0; rnd < 2; rnd++) {
            int o = tid * 16 + rnd * 4096;     // byte offset into tile
            int r = o >> 6;                    // tile row (64 B rows)
            int ke = (o & 63) >> 1;            // k element offset
            *(half8*)((char*)As + o) = *(const half8*)(A  + (size_t)(row0 + r) * 512 + kt * 32 + ke);
            *(half8*)((char*)Bs + o) = *(const half8*)(Bt + (size_t)(col0 + r) * 512 + kt * 32 + ke);
        }
        __syncthreads();
        half8 af[4], bf[4];
        #pragma unroll
        for (int mt = 0; mt < 4; mt++)
            af[mt] = *(const half8*)(As + (wr + mt * 16 + lr) * 32 + q * 8);
        #pragma unroll
        for (int ct = 0; ct < 4; ct++)
            bf[ct] = *(const half8*)(Bs + (wc + ct * 16 + lr) * 32 + q * 8);
        #pragma unroll
        for (int mt = 0; mt < 4; mt++)
            #pragma unroll
            for (int ct = 0; ct < 4; ct++)
                acc[mt][ct] = __builtin_amdgcn_mfma_f32_16x16x32_f16(af[mt], bf[ct], acc[mt][ct], 0, 0, 0);
    }
    // epilogue: C row -> (t = row & 511, b = row >> 9); scatter into new layout
    #pragma unroll
    for (int mt = 0; mt < 4; mt++) {
        #pragma unroll
        for (int r = 0; r < 4; r++) {
            int row = row0 + wr + mt * 16 + q * 4 + r;
            int t = row & 511, b = row >> 9;
            #pragma unroll
            for (int ct = 0; ct < 4; ct++) {
                int col = col0 + wc + ct * 16 + lr;
                int hid = col & 511, gate = col >> 9;
                int wgd = hid >> 4, u = hid & 15;
                xp[(size_t)(((t * 32 + wgd) * 64 + b)) * 64 + u * 4 + gate] =
                    (_Float16)acc[mt][ct][r];
            }
        }
    }
}

// ---------------------------------------------------------------------------
// 4) Recurrent scan — POISON-TAGGED DATA-POLL exchange (no flags, no barriers
//    inside the loop).
//    hb: TRIPLE buffer, 3 x 8192 ull (3 x 64 KB), memset to 0xFF by launcher.
//    An 8B unit of 4 x f16 0xFFFF (all-NaN) can never be a published h
//    (|h| <= 1), so it is a safe "not yet written" sentinel.
//    Per iteration t each WG:
//      - reads  buf[t%3]      (polls units until != POISON; the poll IS the load)
//      - writes buf[(t+1)%3]  (fire-and-forget 8B atomic stores, no drain/flag)
//      - poisons its own slice of buf[(t+2)%3] (provably consumed by all WGs:
//        reaching iter t requires everyone's h_t publish, which follows their
//        iter t-1 reads of that buffer).
//    Ordering poison(t) -> publish(t+1) to the same addresses is enforced by a
//    vmcnt(0) immediately before the publish — free, since every outstanding
//    vmem op at that point is >= 1 iteration old.
//    Waves are fully decoupled: scr is per-wave, wlds is read-only after init.
// ---------------------------------------------------------------------------
__global__ void __launch_bounds__(256, 1) lstm_scan(
    const _Float16* __restrict__ xp,    // [t][wg][b][u][gate] f16
    const _Float16* __restrict__ wt,    // Wt_hh [2048][512] f16
    _Float16* __restrict__ hb,          // 3 x 8192 ull poison-tagged h buffers
    const float* __restrict__ bias,     // [2048]
    const float* __restrict__ h0,       // [64][512]
    const float* __restrict__ c0,       // [64][512]
    float* __restrict__ out) {          // hidden_seq | h_T | c_T
    __shared__ _Float16 wlds[16384];    // 32 cols (gates i,f) x 512 k = 32 KB
    __shared__ _Float16 scr[4 * 320];   // per-wave 16x16 transpose scratch, row stride 20
    const int wg = blockIdx.x;          // 0..31
    const int tid = threadIdx.x;
    const int w = tid >> 6;             // wave 0..3
    const int l = tid & 63;
    const int lr = l & 15;
    const int q = l >> 4;
    const int myhid = wg * 16 + lr;
    _Float16* scrw = scr + w * 320;
    const ull POISON = ~0ull;

    // Stage gates 0,1 (i,f) into LDS. Column n = gate*16+u <- Wt row gate*512+wg*16+u.
    // Granule swizzle: 16B granule g stored at g ^ (n & 7) -> conflict-free frag reads.
    for (int idx = tid; idx < 2048; idx += 256) {
        int n = idx >> 6, g = idx & 63;
        int gate = n >> 4, u = n & 15;
        half8 v = *(const half8*)(wt + (size_t)(gate * 512 + wg * 16 + u) * 512 + g * 8);
        *(half8*)(wlds + n * 512 + ((g ^ (n & 7)) * 8)) = v;
    }
    // Gates 2,3 (g,o) into registers: wreg[kt][gg] = B-frag (n = (2+gg)*16+lr, k = kt*32+q*8)
    half8 wreg[16][2];
    #pragma unroll
    for (int kt = 0; kt < 16; kt++)
        #pragma unroll
        for (int gg = 0; gg < 2; gg++)
            wreg[kt][gg] = *(const half8*)(wt + (size_t)((2 + gg) * 512 + wg * 16 + lr) * 512 + kt * 32 + q * 8);

    // Init h slot 0 from h0 — FULL 8B atomic units (a torn unit could defeat
    // the poison check, so each thread packs+stores one complete ull).
    {
        int b = tid >> 2, u4 = (tid & 3) * 4;   // 256 units = this WG's slice
        union { _Float16 h[4]; ull u; } pk;
        #pragma unroll
        for (int k2 = 0; k2 < 4; k2++)
            pk.h[k2] = (_Float16)h0[b * 512 + wg * 16 + u4 + k2];
        __hip_atomic_store((ull*)hb + wg * 256 + tid, pk.u,
                           __ATOMIC_RELAXED, __HIP_MEMORY_SCOPE_AGENT);
    }

    float bs[4], c[4];
    #pragma unroll
    for (int g4 = 0; g4 < 4; g4++) bs[g4] = bias[g4 * 512 + myhid];
    #pragma unroll
    for (int r = 0; r < 4; r++) c[r] = c0[(w * 16 + q * 4 + r) * 512 + myhid];

    __syncthreads();   // wlds visible to all waves (only barrier in the kernel)

    int pr = 0, pw = 1, pp = 2;   // read / write / poison buffer indices (t%3 rotation)
    for (int t = 0; t < 512; t++) {
        // xp prefetch — raw half4; f16->f32 conversion deferred past the poll so
        // the HBM latency fully overlaps polling.
        half4 xv[4];
        #pragma unroll
        for (int r = 0; r < 4; r++) {
            int b = w * 16 + q * 4 + r;
            xv[r] = *(const half4*)(xp + (((size_t)t * 32 + wg) * 64 + b) * 64 + lr * 4);
        }

        // Data-poll: load A-fragments, retry while any 8B unit is still poison.
        // Reloading an already-fresh unit is idempotent (each buffer is written
        // exactly once per iteration), so the simple all-reload loop is safe.
        const ull* hsrc = (const ull*)hb + (size_t)pr * 8192;
        const int b0 = w * 16 + lr;
        union HU { ull u[2]; half8 v; } a[16];
        int stale;
        do {
            stale = 0;
            #pragma unroll
            for (int kt = 0; kt < 16; kt++) {
                int idx = (2 * kt + (q >> 1)) * 256 + b0 * 4 + (q & 1) * 2;
                ull u0 = __hip_atomic_load(hsrc + idx,     __ATOMIC_RELAXED, __HIP_MEMORY_SCOPE_AGENT);
                ull u1 = __hip_atomic_load(hsrc + idx + 1, __ATOMIC_RELAXED, __HIP_MEMORY_SCOPE_AGENT);
                a[kt].u[0] = u0;
                a[kt].u[1] = u1;
                stale |= (int)(u0 == POISON) | (int)(u1 == POISON);
            }
        } while (stale);

        // MFMA: two interleaved 8-deep accumulator chains per gate (halves the
        // serial MFMA dependency depth vs one 16-deep chain).
        floatx4 zz = {0.f, 0.f, 0.f, 0.f};
        floatx4 acc[4] = {zz, zz, zz, zz};
        floatx4 acc2[4] = {zz, zz, zz, zz};
        #pragma unroll
        for (int kt = 0; kt < 16; kt++) {
            half8 bL[2];
            #pragma unroll
            for (int g4 = 0; g4 < 2; g4++) {
                int n = g4 * 16 + lr;
                bL[g4] = *(const half8*)(wlds + n * 512 + (((kt * 4 + q) ^ (n & 7)) * 8));
            }
            if ((kt & 1) == 0) {
                acc[0] = __builtin_amdgcn_mfma_f32_16x16x32_f16(a[kt].v, bL[0], acc[0], 0, 0, 0);
                acc[1] = __builtin_amdgcn_mfma_f32_16x16x32_f16(a[kt].v, bL[1], acc[1], 0, 0, 0);
                acc[2] = __builtin_amdgcn_mfma_f32_16x16x32_f16(a[kt].v, wreg[kt][0], acc[2], 0, 0, 0);
                acc[3] = __builtin_amdgcn_mfma_f32_16x16x32_f16(a[kt].v, wreg[kt][1], acc[3], 0, 0, 0);
            } else {
                acc2[0] = __builtin_amdgcn_mfma_f32_16x16x32_f16(a[kt].v, bL[0], acc2[0], 0, 0, 0);
                acc2[1] = __builtin_amdgcn_mfma_f32_16x16x32_f16(a[kt].v, bL[1], acc2[1], 0, 0, 0);
                acc2[2] = __builtin_amdgcn_mfma_f32_16x16x32_f16(a[kt].v, wreg[kt][0], acc2[2], 0, 0, 0);
                acc2[3] = __builtin_amdgcn_mfma_f32_16x16x32_f16(a[kt].v, wreg[kt][1], acc2[3], 0, 0, 0);
            }
        }

        // Cell update; stage h tile into LDS for in-wave transpose
        float hv[4];
        #pragma unroll
        for (int r = 0; r < 4; r++) {
            float gi = acc[0][r] + acc2[0][r] + (float)xv[r][0] + bs[0];
            float gf = acc[1][r] + acc2[1][r] + (float)xv[r][1] + bs[1];
            float gg = acc[2][r] + acc2[2][r] + (float)xv[r][2] + bs[2];
            float go = acc[3][r] + acc2[3][r] + (float)xv[r][3] + bs[3];
            float i_ = sigm(gi), f_ = sigm(gf), gv = tanh_(gg), o_ = sigm(go);
            c[r] = f_ * c[r] + i_ * gv;
            float h = o_ * tanh_(c[r]);
            hv[r] = h;
            scrw[(q * 4 + r) * 20 + lr] = (_Float16)h;   // row = local b, col = u
        }
        asm volatile("s_waitcnt lgkmcnt(0)" ::: "memory");  // in-wave transpose ready
        // lane l -> (local b = l>>2, u = (l&3)*4): one contiguous 8B chunk
        union { half4 h; ull u; } pk;
        pk.h = *(const half4*)(scrw + (l >> 2) * 20 + (l & 3) * 4);

        // Order poison(t-1) before publish(t) (same addresses). All outstanding
        // vmem here is >= 1 iteration old -> near-zero wait.
        asm volatile("s_waitcnt vmcnt(0)" ::: "memory");

        // Fire-and-forget publish + poison; consumers detect via the data itself.
        __hip_atomic_store((ull*)hb + (size_t)pw * 8192 + wg * 256 + w * 64 + l, pk.u,
                           __ATOMIC_RELAXED, __HIP_MEMORY_SCOPE_AGENT);
        __hip_atomic_store((ull*)hb + (size_t)pp * 8192 + wg * 256 + w * 64 + l, POISON,
                           __ATOMIC_RELAXED, __HIP_MEMORY_SCOPE_AGENT);

        // Off-critical-path output stores (normal, cached)
        #pragma unroll
        for (int r = 0; r < 4; r++) {
            int b = w * 16 + q * 4 + r;
            out[(size_t)b * 262144 + (size_t)t * 512 + myhid] = hv[r];
            if (t == 511) {
                out[16777216 + b * 512 + myhid] = hv[r];             // h_T
                out[16777216 + 32768 + b * 512 + myhid] = c[r];      // c_T
            }
        }

        int tmp = pr; pr = pw; pw = pp; pp = tmp;   // rotate t%3 buffers
    }
}

// ---------------------------------------------------------------------------
// launch
// ---------------------------------------------------------------------------
extern "C" void kernel_launch(void* const* d_in, const int* in_sizes, int n_in,
                              void* d_out, int out_size, void* d_ws, size_t ws_size,
                              hipStream_t stream) {
    const float* x    = (const float*)d_in[0];
    const float* wih  = (const float*)d_in[1];
    const float* whh  = (const float*)d_in[2];
    const float* bias = (const float*)d_in[3];
    const float* h0   = (const float*)d_in[4];
    const float* c0   = (const float*)d_in[5];
    float* out = (float*)d_out;

    char* ws = (char*)d_ws;
    _Float16* x16  = (_Float16*)(ws);                 // 32 MB
    _Float16* wtih = (_Float16*)(ws + 33554432);      // 2 MB (dead after gemm_xproj)
    _Float16* wthh = (_Float16*)(ws + 35651584);      // 2 MB
    _Float16* xp   = (_Float16*)(ws + 37748736);      // 128 MB
    // hb (3 x 64 KB poison-tagged h buffers) ALIASES the wtih region, which is
    // dead once gemm_xproj has run — the poison memset is enqueued after it.
    _Float16* hb   = (_Float16*)(ws + 33554432);

    // x fp32 -> f16
    convert_f32_f16<<<16384, 256, 0, stream>>>(x, x16, BATCH * SEQ * IS / 4);
    // weight transposes (fp32 [512][2048] -> f16 [2048][512])
    transpose_w<<<256, 256, 0, stream>>>(wih, wtih);
    transpose_w<<<256, 256, 0, stream>>>(whh, wthh);
    // input projection (writes scan-friendly xp layout)
    gemm_xproj<<<4096, 256, 0, stream>>>(x16, wtih, xp);
    // Poison all 3 h-exchange buffers (after gemm_xproj: hb aliases wtih).
    hipMemsetAsync(hb, 0xFF, 196608, stream);
    // recurrent scan — REGULAR launch (32 blocks trivially co-resident on 256 CUs)
    lstm_scan<<<32, 256, 0, stream>>>(xp, wthh, hb, bias, h0, c0, out);
}

// Round 4
// 2096.247 us; speedup vs baseline: 1.1411x; 1.1122x over previous
//
#include <hip/hip_runtime.h>

// Problem constants
#define SEQ   512
#define BATCH 64
#define IS    512
#define HS    512
#define G4    2048   // 4*HS

typedef _Float16 half8 __attribute__((ext_vector_type(8)));
typedef _Float16 half4 __attribute__((ext_vector_type(4)));
typedef float floatx4 __attribute__((ext_vector_type(4)));
typedef unsigned long long ull;

__device__ __forceinline__ float sigm(float x) {
    return 1.0f / (1.0f + __expf(-x));
}
__device__ __forceinline__ float tanh_(float x) {
    float e = __expf(-2.0f * fabsf(x));
    float r = (1.0f - e) / (1.0f + e);
    return copysignf(r, x);
}

// ---------------------------------------------------------------------------
// 1) fp32 -> f16 convert (x), vectorized 4-wide
// ---------------------------------------------------------------------------
__global__ void convert_f32_f16(const float* __restrict__ in,
                                _Float16* __restrict__ out, int n4) {
    int i = blockIdx.x * blockDim.x + threadIdx.x;
    if (i < n4) {
        float4 v = ((const float4*)in)[i];
        half4 o = { (_Float16)v.x, (_Float16)v.y, (_Float16)v.z, (_Float16)v.w };
        ((half4*)out)[i] = o;
    }
}

// ---------------------------------------------------------------------------
// 2) W [512][2048] fp32  ->  Wt [2048][512] f16  (k-contiguous for MFMA frags)
// ---------------------------------------------------------------------------
__global__ void transpose_w(const float* __restrict__ in, _Float16* __restrict__ out) {
    __shared__ _Float16 tile[64][72];   // +8 pad
    int bk = blockIdx.x & 7;            // k tile  (512/64)
    int bn = blockIdx.x >> 3;           // n tile  (2048/64)
    int c = threadIdx.x & 63;
    int r4 = threadIdx.x >> 6;          // 0..3
    #pragma unroll
    for (int rr = 0; rr < 16; rr++) {
        int k = rr * 4 + r4;
        tile[k][c] = (_Float16)in[(size_t)(bk * 64 + k) * 2048 + bn * 64 + c];
    }
    __syncthreads();
    #pragma unroll
    for (int rr = 0; rr < 16; rr++) {
        int n = rr * 4 + r4;
        out[(size_t)(bn * 64 + n) * 512 + bk * 64 + c] = tile[c][n];
    }
}

// ---------------------------------------------------------------------------
// 3) x_proj GEMM. Output layout (f16) for the 128-WG scan:
//    wg = (b>>4)*32 + (hid>>4)   (batch-group bg = b>>4, hid-group hg)
//    elem = ((t*128 + wg)*16 + (b&15))*64 + (hid&15)*4 + gate
//    -> scan thread reads one half4 (4 gates) per (b_local, u), coalesced.
// ---------------------------------------------------------------------------
__global__ void __launch_bounds__(256, 2) gemm_xproj(
    const _Float16* __restrict__ A,
    const _Float16* __restrict__ Bt,
    _Float16* __restrict__ xp) {
    __shared__ _Float16 As[4096];   // 128 rows x 32 k
    __shared__ _Float16 Bs[4096];   // 128 n-rows x 32 k
    const int tid = threadIdx.x;
    const int w = tid >> 6, l = tid & 63, lr = l & 15, q = l >> 4;
    const int bm = blockIdx.x & 255, bn = blockIdx.x >> 8;
    const int row0 = bm * 128, col0 = bn * 128;
    const int wr = (w >> 1) * 64, wc = (w & 1) * 64;

    floatx4 zz = {0.f, 0.f, 0.f, 0.f};
    floatx4 acc[4][4];
    #pragma unroll
    for (int mt = 0; mt < 4; mt++)
        #pragma unroll
        for (int ct = 0; ct < 4; ct++) acc[mt][ct] = zz;

    for (int kt = 0; kt < 16; kt++) {
        __syncthreads();
        #pragma unroll
        for (int rnd = 0; rnd < 2; rnd++) {
            int o = tid * 16 + rnd * 4096;     // byte offset into tile
            int r = o >> 6;                    // tile row (64 B rows)
            int ke = (o & 63) >> 1;            // k element offset
            *(half8*)((char*)As + o) = *(const half8*)(A  + (size_t)(row0 + r) * 512 + kt * 32 + ke);
            *(half8*)((char*)Bs + o) = *(const half8*)(Bt + (size_t)(col0 + r) * 512 + kt * 32 + ke);
        }
        __syncthreads();
        half8 af[4], bf[4];
        #pragma unroll
        for (int mt = 0; mt < 4; mt++)
            af[mt] = *(const half8*)(As + (wr + mt * 16 + lr) * 32 + q * 8);
        #pragma unroll
        for (int ct = 0; ct < 4; ct++)
            bf[ct] = *(const half8*)(Bs + (wc + ct * 16 + lr) * 32 + q * 8);
        #pragma unroll
        for (int mt = 0; mt < 4; mt++)
            #pragma unroll
            for (int ct = 0; ct < 4; ct++)
                acc[mt][ct] = __builtin_amdgcn_mfma_f32_16x16x32_f16(af[mt], bf[ct], acc[mt][ct], 0, 0, 0);
    }
    // epilogue: C row -> (t = row & 511, b = row >> 9); scatter into scan layout
    #pragma unroll
    for (int mt = 0; mt < 4; mt++) {
        #pragma unroll
        for (int r = 0; r < 4; r++) {
            int row = row0 + wr + mt * 16 + q * 4 + r;
            int t = row & 511, b = row >> 9;
            #pragma unroll
            for (int ct = 0; ct < 4; ct++) {
                int col = col0 + wc + ct * 16 + lr;
                int hid = col & 511, gate = col >> 9;
                int wgd = (b >> 4) * 32 + (hid >> 4);
                int bl = b & 15, u = hid & 15;
                xp[(size_t)(((t * 128 + wgd) * 16 + bl)) * 64 + u * 4 + gate] =
                    (_Float16)acc[mt][ct][r];
            }
        }
    }
}

// ---------------------------------------------------------------------------
// 4) Recurrent scan — BATCH-PARTITIONED, SINGLE-WAVE WGs, BARRIER-FREE loop.
//    128 WGs x 64 threads. wg = bg*32 + hg: batch-group bg (16 batches),
//    hid-group hg (16 hidden units). The 4 batch-groups are fully
//    INDEPENDENT pipelines (jitter does not couple across groups).
//    Exchange per group: 16 b x 512 hid f16 = 16 KB, double-buffered.
//      hb ull layout: [buf][bg] region of 2048 ull; unit (b*128 + hid/4).
//    Signaling: 8 counter lines per group (128 B apart); each WG atomicAdds 1
//    to line (hg&7) after its publish is drained (vmcnt(0) = release).
//    Line value reaches 4*(t+2) when all its 4 WGs published step t.
//    Consumer: all 64 lanes load line (l&7) -> __all(v >= 4*(t+1)) -> compiler
//    fence + sched_barrier (acquire; HW issues in order after the branch).
//    Double-buffer WAR safety (R0 invariant): P overwrites buf[b2] at step t
//    only after seeing all counters for step t => every consumer C published
//    h_t => C's step-t-1 reads of buf[b2] were serviced before C's drained
//    publish => before C's add => before P's write. Safe.
//    NO __syncthreads anywhere in the loop (single wave per WG).
// ---------------------------------------------------------------------------
__global__ void __launch_bounds__(64, 1) lstm_scan(
    const _Float16* __restrict__ xp,    // [t][wg][b_local][u][gate] f16
    const _Float16* __restrict__ wt,    // Wt_hh [2048][512] f16
    _Float16* __restrict__ hb,          // 2 x 4 x 2048 ull h double buffer
    const float* __restrict__ bias,     // [2048]
    const float* __restrict__ h0,       // [64][512]
    const float* __restrict__ c0,       // [64][512]
    float* __restrict__ out,            // hidden_seq | h_T | c_T
    int* __restrict__ cnt) {            // 4 groups x 8 lines x 128 B
    __shared__ _Float16 wlds[16384];    // 32 cols (gates i,f) x 512 k = 32 KB
    __shared__ _Float16 scr[320];       // 16x16 transpose scratch, row stride 20
    const int wg = blockIdx.x;          // 0..127
    const int bg = wg >> 5;             // batch group 0..3
    const int hg = wg & 31;             // hid group 0..31
    const int l  = threadIdx.x;         // 0..63 (single wave)
    const int lr = l & 15;
    const int q  = l >> 4;
    const int myhid = hg * 16 + lr;

    // Stage gates 0,1 (i,f) into LDS. Column n = gate*16+u <- Wt row gate*512+hg*16+u.
    // Granule swizzle: 16B granule g stored at g ^ (n & 7) -> conflict-free frag reads.
    for (int idx = l; idx < 2048; idx += 64) {
        int n = idx >> 6, g = idx & 63;
        int gate = n >> 4, u = n & 15;
        half8 v = *(const half8*)(wt + (size_t)(gate * 512 + hg * 16 + u) * 512 + g * 8);
        *(half8*)(wlds + n * 512 + ((g ^ (n & 7)) * 8)) = v;
    }
    // Gates 2,3 (g,o) into registers: wreg[kt][gg] = B-frag (n = (2+gg)*16+lr)
    half8 wreg[16][2];
    #pragma unroll
    for (int kt = 0; kt < 16; kt++)
        #pragma unroll
        for (int gg = 0; gg < 2; gg++)
            wreg[kt][gg] = *(const half8*)(wt + (size_t)((2 + gg) * 512 + hg * 16 + lr) * 512 + kt * 32 + q * 8);

    // Init h buf0 from h0: this WG's 16 b x 16 hid slice, full-8B units.
    {
        int b = l >> 2, u4 = (l & 3) * 4;
        union { _Float16 h[4]; ull u; } pk;
        #pragma unroll
        for (int k2 = 0; k2 < 4; k2++)
            pk.h[k2] = (_Float16)h0[(bg * 16 + b) * 512 + hg * 16 + u4 + k2];
        __hip_atomic_store((ull*)hb + bg * 2048 + b * 128 + hg * 4 + (l & 3), pk.u,
                           __ATOMIC_RELAXED, __HIP_MEMORY_SCOPE_AGENT);
    }

    float bs[4], c[4];
    #pragma unroll
    for (int g4 = 0; g4 < 4; g4++) bs[g4] = bias[g4 * 512 + myhid];
    #pragma unroll
    for (int r = 0; r < 4; r++) c[r] = c0[(bg * 16 + q * 4 + r) * 512 + myhid];

    // Release init publish, then count in.
    asm volatile("s_waitcnt vmcnt(0)" ::: "memory");
    if (l == 0)
        __hip_atomic_fetch_add(&cnt[(bg * 8 + (hg & 7)) * 32], 1,
                               __ATOMIC_RELAXED, __HIP_MEMORY_SCOPE_AGENT);

    int* const cline = &cnt[(bg * 8 + (l & 7)) * 32];   // this lane's poll line

    for (int t = 0; t < 512; t++) {
        // xp prefetch — issued before the poll so HBM latency hides under detect
        half4 xv[4];
        #pragma unroll
        for (int r = 0; r < 4; r++)
            xv[r] = *(const half4*)(xp + (((size_t)t * 128 + wg) * 16 + q * 4 + r) * 64 + lr * 4);

        // Detect: all group producers published step t (8 lines, 4 adds each)
        const int tgt = 4 * (t + 1);
        while (!__all(__hip_atomic_load(cline, __ATOMIC_RELAXED,
                                        __HIP_MEMORY_SCOPE_AGENT) >= tgt)) { }
        asm volatile("" ::: "memory");          // acquire: no compiler motion
        __builtin_amdgcn_sched_barrier(0);      // across the poll

        // Single data sweep: this group's 16 KB, 32 x 8B agent loads per lane
        const ull* hsrc = (const ull*)hb + (size_t)((t & 1) * 4 + bg) * 2048;
        union HU { ull u[2]; half8 v; } a[16];
        #pragma unroll
        for (int kt = 0; kt < 16; kt++) {
            int idx = lr * 128 + kt * 8 + q * 2;
            a[kt].u[0] = __hip_atomic_load(hsrc + idx,     __ATOMIC_RELAXED, __HIP_MEMORY_SCOPE_AGENT);
            a[kt].u[1] = __hip_atomic_load(hsrc + idx + 1, __ATOMIC_RELAXED, __HIP_MEMORY_SCOPE_AGENT);
        }

        // MFMA: two interleaved 8-deep accumulator chains per gate
        floatx4 zz = {0.f, 0.f, 0.f, 0.f};
        floatx4 acc[4] = {zz, zz, zz, zz};
        floatx4 acc2[4] = {zz, zz, zz, zz};
        #pragma unroll
        for (int kt = 0; kt < 16; kt++) {
            half8 bL[2];
            #pragma unroll
            for (int g4 = 0; g4 < 2; g4++) {
                int n = g4 * 16 + lr;
                bL[g4] = *(const half8*)(wlds + n * 512 + (((kt * 4 + q) ^ (n & 7)) * 8));
            }
            if ((kt & 1) == 0) {
                acc[0] = __builtin_amdgcn_mfma_f32_16x16x32_f16(a[kt].v, bL[0], acc[0], 0, 0, 0);
                acc[1] = __builtin_amdgcn_mfma_f32_16x16x32_f16(a[kt].v, bL[1], acc[1], 0, 0, 0);
                acc[2] = __builtin_amdgcn_mfma_f32_16x16x32_f16(a[kt].v, wreg[kt][0], acc[2], 0, 0, 0);
                acc[3] = __builtin_amdgcn_mfma_f32_16x16x32_f16(a[kt].v, wreg[kt][1], acc[3], 0, 0, 0);
            } else {
                acc2[0] = __builtin_amdgcn_mfma_f32_16x16x32_f16(a[kt].v, bL[0], acc2[0], 0, 0, 0);
                acc2[1] = __builtin_amdgcn_mfma_f32_16x16x32_f16(a[kt].v, bL[1], acc2[1], 0, 0, 0);
                acc2[2] = __builtin_amdgcn_mfma_f32_16x16x32_f16(a[kt].v, wreg[kt][0], acc2[2], 0, 0, 0);
                acc2[3] = __builtin_amdgcn_mfma_f32_16x16x32_f16(a[kt].v, wreg[kt][1], acc2[3], 0, 0, 0);
            }
        }

        // Cell update; stage h tile in LDS for in-wave transpose
        float hv[4];
        #pragma unroll
        for (int r = 0; r < 4; r++) {
            float gi = acc[0][r] + acc2[0][r] + (float)xv[r][0] + bs[0];
            float gf = acc[1][r] + acc2[1][r] + (float)xv[r][1] + bs[1];
            float gg = acc[2][r] + acc2[2][r] + (float)xv[r][2] + bs[2];
            float go = acc[3][r] + acc2[3][r] + (float)xv[r][3] + bs[3];
            float i_ = sigm(gi), f_ = sigm(gf), gv = tanh_(gg), o_ = sigm(go);
            c[r] = f_ * c[r] + i_ * gv;
            float h = o_ * tanh_(c[r]);
            hv[r] = h;
            scr[(q * 4 + r) * 20 + lr] = (_Float16)h;   // row = local b, col = u
        }
        asm volatile("s_waitcnt lgkmcnt(0)" ::: "memory");  // transpose ready
        union { half4 h; ull u; } pk;
        pk.h = *(const half4*)(scr + (l >> 2) * 20 + (l & 3) * 4);

        // Publish h_{t+1} slice, drain (release), count in. No barrier needed.
        __hip_atomic_store((ull*)hb + (size_t)(((t + 1) & 1) * 4 + bg) * 2048
                               + (l >> 2) * 128 + hg * 4 + (l & 3), pk.u,
                           __ATOMIC_RELAXED, __HIP_MEMORY_SCOPE_AGENT);
        asm volatile("s_waitcnt vmcnt(0)" ::: "memory");
        if (l == 0)
            __hip_atomic_fetch_add(&cnt[(bg * 8 + (hg & 7)) * 32], 1,
                                   __ATOMIC_RELAXED, __HIP_MEMORY_SCOPE_AGENT);

        // Off-critical-path output stores (normal, cached)
        #pragma unroll
        for (int r = 0; r < 4; r++) {
            int b = bg * 16 + q * 4 + r;
            out[(size_t)b * 262144 + (size_t)t * 512 + myhid] = hv[r];
            if (t == 511) {
                out[16777216 + b * 512 + myhid] = hv[r];             // h_T
                out[16777216 + 32768 + b * 512 + myhid] = c[r];      // c_T
            }
        }
    }
}

// ---------------------------------------------------------------------------
// launch
// ---------------------------------------------------------------------------
extern "C" void kernel_launch(void* const* d_in, const int* in_sizes, int n_in,
                              void* d_out, int out_size, void* d_ws, size_t ws_size,
                              hipStream_t stream) {
    const float* x    = (const float*)d_in[0];
    const float* wih  = (const float*)d_in[1];
    const float* whh  = (const float*)d_in[2];
    const float* bias = (const float*)d_in[3];
    const float* h0   = (const float*)d_in[4];
    const float* c0   = (const float*)d_in[5];
    float* out = (float*)d_out;

    char* ws = (char*)d_ws;
    _Float16* x16  = (_Float16*)(ws);                 // 32 MB
    _Float16* wtih = (_Float16*)(ws + 33554432);      // 2 MB
    _Float16* wthh = (_Float16*)(ws + 35651584);      // 2 MB
    _Float16* xp   = (_Float16*)(ws + 37748736);      // 128 MB, ends 171966464
    // Control region past xp's end — touched by no other kernel.
    _Float16* hb   = (_Float16*)(ws + 171966464);     // 128 KB (2 x 4 x 16 KB)
    int*      cnt  = (int*)(ws + 172097536);          // 4 KB (32 lines x 128 B)

    // x fp32 -> f16
    convert_f32_f16<<<16384, 256, 0, stream>>>(x, x16, BATCH * SEQ * IS / 4);
    // weight transposes (fp32 [512][2048] -> f16 [2048][512])
    transpose_w<<<256, 256, 0, stream>>>(wih, wtih);
    transpose_w<<<256, 256, 0, stream>>>(whh, wthh);
    // input projection (writes 128-WG scan layout)
    gemm_xproj<<<4096, 256, 0, stream>>>(x16, wtih, xp);
    // counters = 0
    hipMemsetAsync(cnt, 0, 4096, stream);
    // recurrent scan — 128 single-wave WGs, 4 independent batch-groups
    lstm_scan<<<128, 64, 0, stream>>>(xp, wthh, hb, bias, h0, c0, out, cnt);
}

// Round 5
// 2051.750 us; speedup vs baseline: 1.1658x; 1.0217x over previous
//
#include <hip/hip_runtime.h>

// Problem constants
#define SEQ   512
#define BATCH 64
#define IS    512
#define HS    512
#define G4    2048   // 4*HS

typedef _Float16 half8 __attribute__((ext_vector_type(8)));
typedef _Float16 half4 __attribute__((ext_vector_type(4)));
typedef float floatx4 __attribute__((ext_vector_type(4)));
typedef unsigned long long ull;

__device__ __forceinline__ float sigm(float x) {
    return 1.0f / (1.0f + __expf(-x));
}
__device__ __forceinline__ float tanh_(float x) {
    float e = __expf(-2.0f * fabsf(x));
    float r = (1.0f - e) / (1.0f + e);
    return copysignf(r, x);
}

// ---------------------------------------------------------------------------
// 1) fp32 -> f16 convert (x), vectorized 4-wide
// ---------------------------------------------------------------------------
__global__ void convert_f32_f16(const float* __restrict__ in,
                                _Float16* __restrict__ out, int n4) {
    int i = blockIdx.x * blockDim.x + threadIdx.x;
    if (i < n4) {
        float4 v = ((const float4*)in)[i];
        half4 o = { (_Float16)v.x, (_Float16)v.y, (_Float16)v.z, (_Float16)v.w };
        ((half4*)out)[i] = o;
    }
}

// ---------------------------------------------------------------------------
// 2) W [512][2048] fp32  ->  Wt [2048][512] f16  (k-contiguous for MFMA frags)
// ---------------------------------------------------------------------------
__global__ void transpose_w(const float* __restrict__ in, _Float16* __restrict__ out) {
    __shared__ _Float16 tile[64][72];   // +8 pad
    int bk = blockIdx.x & 7;            // k tile  (512/64)
    int bn = blockIdx.x >> 3;           // n tile  (2048/64)
    int c = threadIdx.x & 63;
    int r4 = threadIdx.x >> 6;          // 0..3
    #pragma unroll
    for (int rr = 0; rr < 16; rr++) {
        int k = rr * 4 + r4;
        tile[k][c] = (_Float16)in[(size_t)(bk * 64 + k) * 2048 + bn * 64 + c];
    }
    __syncthreads();
    #pragma unroll
    for (int rr = 0; rr < 16; rr++) {
        int n = rr * 4 + r4;
        out[(size_t)(bn * 64 + n) * 512 + bk * 64 + c] = tile[c][n];
    }
}

// ---------------------------------------------------------------------------
// 3) x_proj GEMM. Output layout (f16) for the 128-WG scan:
//    wg = (b>>4)*32 + (hid>>4)   (batch-group bg = b>>4, hid-group hg)
//    elem = ((t*128 + wg)*16 + (b&15))*64 + (hid&15)*4 + gate
// ---------------------------------------------------------------------------
__global__ void __launch_bounds__(256, 2) gemm_xproj(
    const _Float16* __restrict__ A,
    const _Float16* __restrict__ Bt,
    _Float16* __restrict__ xp) {
    __shared__ _Float16 As[4096];   // 128 rows x 32 k
    __shared__ _Float16 Bs[4096];   // 128 n-rows x 32 k
    const int tid = threadIdx.x;
    const int w = tid >> 6, l = tid & 63, lr = l & 15, q = l >> 4;
    const int bm = blockIdx.x & 255, bn = blockIdx.x >> 8;
    const int row0 = bm * 128, col0 = bn * 128;
    const int wr = (w >> 1) * 64, wc = (w & 1) * 64;

    floatx4 zz = {0.f, 0.f, 0.f, 0.f};
    floatx4 acc[4][4];
    #pragma unroll
    for (int mt = 0; mt < 4; mt++)
        #pragma unroll
        for (int ct = 0; ct < 4; ct++) acc[mt][ct] = zz;

    for (int kt = 0; kt < 16; kt++) {
        __syncthreads();
        #pragma unroll
        for (int rnd = 0; rnd < 2; rnd++) {
            int o = tid * 16 + rnd * 4096;     // byte offset into tile
            int r = o >> 6;                    // tile row (64 B rows)
            int ke = (o & 63) >> 1;            // k element offset
            *(half8*)((char*)As + o) = *(const half8*)(A  + (size_t)(row0 + r) * 512 + kt * 32 + ke);
            *(half8*)((char*)Bs + o) = *(const half8*)(Bt + (size_t)(col0 + r) * 512 + kt * 32 + ke);
        }
        __syncthreads();
        half8 af[4], bf[4];
        #pragma unroll
        for (int mt = 0; mt < 4; mt++)
            af[mt] = *(const half8*)(As + (wr + mt * 16 + lr) * 32 + q * 8);
        #pragma unroll
        for (int ct = 0; ct < 4; ct++)
            bf[ct] = *(const half8*)(Bs + (wc + ct * 16 + lr) * 32 + q * 8);
        #pragma unroll
        for (int mt = 0; mt < 4; mt++)
            #pragma unroll
            for (int ct = 0; ct < 4; ct++)
                acc[mt][ct] = __builtin_amdgcn_mfma_f32_16x16x32_f16(af[mt], bf[ct], acc[mt][ct], 0, 0, 0);
    }
    // epilogue: C row -> (t = row & 511, b = row >> 9); scatter into scan layout
    #pragma unroll
    for (int mt = 0; mt < 4; mt++) {
        #pragma unroll
        for (int r = 0; r < 4; r++) {
            int row = row0 + wr + mt * 16 + q * 4 + r;
            int t = row & 511, b = row >> 9;
            #pragma unroll
            for (int ct = 0; ct < 4; ct++) {
                int col = col0 + wc + ct * 16 + lr;
                int hid = col & 511, gate = col >> 9;
                int wgd = (b >> 4) * 32 + (hid >> 4);
                int bl = b & 15, u = hid & 15;
                xp[(size_t)(((t * 128 + wgd) * 16 + bl)) * 64 + u * 4 + gate] =
                    (_Float16)acc[mt][ct][r];
            }
        }
    }
}

// ---------------------------------------------------------------------------
// 4) Recurrent scan — BATCH-PARTITIONED, SINGLE-WAVE WGs, BARRIER-FREE loop.
//    R5 changes vs R4 (structure identical, serial latency cut):
//    a) EPOCH detection: per-producer epoch word ep[bg*32+hg] in ONE 128 B
//       line per group. Producer: plain drained store (no atomicAdd
//       serialization). Consumer: all 64 lanes poll the single broadcast
//       line (l&31) and __all(v >= t+1). One load per sample.
//    b) xp prefetched ONE STEP AHEAD, issued right after the sweep loads:
//       first use is next iteration -> cold-HBM latency hidden under
//       MFMA+cell+poll, and the poll's vmcnt(0) no longer drains it.
//    c) out stores issued BEFORE the release vmcnt(0): their acks overlap
//       with the publish ack inside one drain (max, not sum), leaving the
//       next poll's first sample clean.
//    Protocol/WAR invariants unchanged from R4 (epoch == counter/4).
// ---------------------------------------------------------------------------
__global__ void __launch_bounds__(64, 1) lstm_scan(
    const _Float16* __restrict__ xp,    // [t][wg][b_local][u][gate] f16
    const _Float16* __restrict__ wt,    // Wt_hh [2048][512] f16
    _Float16* __restrict__ hb,          // 2 x 4 x 2048 ull h double buffer
    const float* __restrict__ bias,     // [2048]
    const float* __restrict__ h0,       // [64][512]
    const float* __restrict__ c0,       // [64][512]
    float* __restrict__ out,            // hidden_seq | h_T | c_T
    int* __restrict__ ep) {             // 4 groups x 32 epoch words (128 B/line)
    __shared__ _Float16 wlds[16384];    // 32 cols (gates i,f) x 512 k = 32 KB
    __shared__ _Float16 scr[320];       // 16x16 transpose scratch, row stride 20
    const int wg = blockIdx.x;          // 0..127
    const int bg = wg >> 5;             // batch group 0..3
    const int hg = wg & 31;             // hid group 0..31
    const int l  = threadIdx.x;         // 0..63 (single wave)
    const int lr = l & 15;
    const int q  = l >> 4;
    const int myhid = hg * 16 + lr;

    // Stage gates 0,1 (i,f) into LDS (granule-swizzled, conflict-free reads)
    for (int idx = l; idx < 2048; idx += 64) {
        int n = idx >> 6, g = idx & 63;
        int gate = n >> 4, u = n & 15;
        half8 v = *(const half8*)(wt + (size_t)(gate * 512 + hg * 16 + u) * 512 + g * 8);
        *(half8*)(wlds + n * 512 + ((g ^ (n & 7)) * 8)) = v;
    }
    // Gates 2,3 (g,o) into registers: wreg[kt][gg] = B-frag (n = (2+gg)*16+lr)
    half8 wreg[16][2];
    #pragma unroll
    for (int kt = 0; kt < 16; kt++)
        #pragma unroll
        for (int gg = 0; gg < 2; gg++)
            wreg[kt][gg] = *(const half8*)(wt + (size_t)((2 + gg) * 512 + hg * 16 + lr) * 512 + kt * 32 + q * 8);

    // Init h buf0 from h0: this WG's 16 b x 16 hid slice, full-8B units.
    {
        int b = l >> 2, u4 = (l & 3) * 4;
        union { _Float16 h[4]; ull u; } pk;
        #pragma unroll
        for (int k2 = 0; k2 < 4; k2++)
            pk.h[k2] = (_Float16)h0[(bg * 16 + b) * 512 + hg * 16 + u4 + k2];
        __hip_atomic_store((ull*)hb + bg * 2048 + b * 128 + hg * 4 + (l & 3), pk.u,
                           __ATOMIC_RELAXED, __HIP_MEMORY_SCOPE_AGENT);
    }

    float bs[4], c[4];
    #pragma unroll
    for (int g4 = 0; g4 < 4; g4++) bs[g4] = bias[g4 * 512 + myhid];
    #pragma unroll
    for (int r = 0; r < 4; r++) c[r] = c0[(bg * 16 + q * 4 + r) * 512 + myhid];

    // xp prefetch for step 0 (pre-loop)
    half4 xv[4];
    #pragma unroll
    for (int r = 0; r < 4; r++)
        xv[r] = *(const half4*)(xp + (((size_t)0 * 128 + wg) * 16 + q * 4 + r) * 64 + lr * 4);

    // Release init publish, then epoch=1 (plain drained store)
    asm volatile("s_waitcnt vmcnt(0)" ::: "memory");
    if (l == 0)
        __hip_atomic_store(&ep[bg * 32 + hg], 1,
                           __ATOMIC_RELAXED, __HIP_MEMORY_SCOPE_AGENT);

    int* const eline = &ep[bg * 32 + (l & 31)];   // this lane's epoch slot

    for (int t = 0; t < 512; t++) {
        // Detect: all 32 group producers published step t. One 128 B line,
        // all lanes sample it; nothing else outstanding (xp/outs drained by
        // the previous release or ~a full step old) -> samples are clean RTTs.
        const int tgt = t + 1;
        while (!__all(__hip_atomic_load(eline, __ATOMIC_RELAXED,
                                        __HIP_MEMORY_SCOPE_AGENT) >= tgt)) { }
        asm volatile("" ::: "memory");          // acquire: no compiler motion
        __builtin_amdgcn_sched_barrier(0);      // across the poll

        // Single data sweep: this group's 16 KB, 32 x 8B agent loads per lane
        const ull* hsrc = (const ull*)hb + (size_t)((t & 1) * 4 + bg) * 2048;
        union HU { ull u[2]; half8 v; } a[16];
        #pragma unroll
        for (int kt = 0; kt < 16; kt++) {
            int idx = lr * 128 + kt * 8 + q * 2;
            a[kt].u[0] = __hip_atomic_load(hsrc + idx,     __ATOMIC_RELAXED, __HIP_MEMORY_SCOPE_AGENT);
            a[kt].u[1] = __hip_atomic_load(hsrc + idx + 1, __ATOMIC_RELAXED, __HIP_MEMORY_SCOPE_AGENT);
        }

        // xp prefetch for t+1, issued NOW (after sweep issue, before MFMA):
        // first use is next iteration -> latency fully hidden. (t=511 wraps
        // to 0; value discarded.)
        half4 xvn[4];
        {
            int tn = (t + 1) & 511;
            #pragma unroll
            for (int r = 0; r < 4; r++)
                xvn[r] = *(const half4*)(xp + (((size_t)tn * 128 + wg) * 16 + q * 4 + r) * 64 + lr * 4);
        }

        // MFMA: two interleaved 8-deep accumulator chains per gate
        floatx4 zz = {0.f, 0.f, 0.f, 0.f};
        floatx4 acc[4] = {zz, zz, zz, zz};
        floatx4 acc2[4] = {zz, zz, zz, zz};
        #pragma unroll
        for (int kt = 0; kt < 16; kt++) {
            half8 bL[2];
            #pragma unroll
            for (int g4 = 0; g4 < 2; g4++) {
                int n = g4 * 16 + lr;
                bL[g4] = *(const half8*)(wlds + n * 512 + (((kt * 4 + q) ^ (n & 7)) * 8));
            }
            if ((kt & 1) == 0) {
                acc[0] = __builtin_amdgcn_mfma_f32_16x16x32_f16(a[kt].v, bL[0], acc[0], 0, 0, 0);
                acc[1] = __builtin_amdgcn_mfma_f32_16x16x32_f16(a[kt].v, bL[1], acc[1], 0, 0, 0);
                acc[2] = __builtin_amdgcn_mfma_f32_16x16x32_f16(a[kt].v, wreg[kt][0], acc[2], 0, 0, 0);
                acc[3] = __builtin_amdgcn_mfma_f32_16x16x32_f16(a[kt].v, wreg[kt][1], acc[3], 0, 0, 0);
            } else {
                acc2[0] = __builtin_amdgcn_mfma_f32_16x16x32_f16(a[kt].v, bL[0], acc2[0], 0, 0, 0);
                acc2[1] = __builtin_amdgcn_mfma_f32_16x16x32_f16(a[kt].v, bL[1], acc2[1], 0, 0, 0);
                acc2[2] = __builtin_amdgcn_mfma_f32_16x16x32_f16(a[kt].v, wreg[kt][0], acc2[2], 0, 0, 0);
                acc2[3] = __builtin_amdgcn_mfma_f32_16x16x32_f16(a[kt].v, wreg[kt][1], acc2[3], 0, 0, 0);
            }
        }

        // Cell update; stage h tile in LDS for in-wave transpose
        float hv[4];
        #pragma unroll
        for (int r = 0; r < 4; r++) {
            float gi = acc[0][r] + acc2[0][r] + (float)xv[r][0] + bs[0];
            float gf = acc[1][r] + acc2[1][r] + (float)xv[r][1] + bs[1];
            float gg = acc[2][r] + acc2[2][r] + (float)xv[r][2] + bs[2];
            float go = acc[3][r] + acc2[3][r] + (float)xv[r][3] + bs[3];
            float i_ = sigm(gi), f_ = sigm(gf), gv = tanh_(gg), o_ = sigm(go);
            c[r] = f_ * c[r] + i_ * gv;
            float h = o_ * tanh_(c[r]);
            hv[r] = h;
            scr[(q * 4 + r) * 20 + lr] = (_Float16)h;   // row = local b, col = u
        }
        asm volatile("s_waitcnt lgkmcnt(0)" ::: "memory");  // transpose ready
        union { half4 h; ull u; } pk;
        pk.h = *(const half4*)(scr + (l >> 2) * 20 + (l & 3) * 4);

        // Publish h_{t+1} slice...
        __hip_atomic_store((ull*)hb + (size_t)(((t + 1) & 1) * 4 + bg) * 2048
                               + (l >> 2) * 128 + hg * 4 + (l & 3), pk.u,
                           __ATOMIC_RELAXED, __HIP_MEMORY_SCOPE_AGENT);
        // ...and out stores BEFORE the release drain: acks overlap (max, not
        // sum), and the next poll's first sample stays clean.
        #pragma unroll
        for (int r = 0; r < 4; r++) {
            int b = bg * 16 + q * 4 + r;
            out[(size_t)b * 262144 + (size_t)t * 512 + myhid] = hv[r];
            if (t == 511) {
                out[16777216 + b * 512 + myhid] = hv[r];             // h_T
                out[16777216 + 32768 + b * 512 + myhid] = c[r];      // c_T
            }
        }
        // Release: drain publish+outs, then epoch store (plain, no atomic)
        asm volatile("s_waitcnt vmcnt(0)" ::: "memory");
        if (l == 0)
            __hip_atomic_store(&ep[bg * 32 + hg], t + 2,
                               __ATOMIC_RELAXED, __HIP_MEMORY_SCOPE_AGENT);

        #pragma unroll
        for (int r = 0; r < 4; r++) xv[r] = xvn[r];
    }
}

// ---------------------------------------------------------------------------
// launch
// ---------------------------------------------------------------------------
extern "C" void kernel_launch(void* const* d_in, const int* in_sizes, int n_in,
                              void* d_out, int out_size, void* d_ws, size_t ws_size,
                              hipStream_t stream) {
    const float* x    = (const float*)d_in[0];
    const float* wih  = (const float*)d_in[1];
    const float* whh  = (const float*)d_in[2];
    const float* bias = (const float*)d_in[3];
    const float* h0   = (const float*)d_in[4];
    const float* c0   = (const float*)d_in[5];
    float* out = (float*)d_out;

    char* ws = (char*)d_ws;
    _Float16* x16  = (_Float16*)(ws);                 // 32 MB
    _Float16* wtih = (_Float16*)(ws + 33554432);      // 2 MB
    _Float16* wthh = (_Float16*)(ws + 35651584);      // 2 MB
    _Float16* xp   = (_Float16*)(ws + 37748736);      // 128 MB, ends 171966464
    // Control region past xp's end — touched by no other kernel.
    _Float16* hb   = (_Float16*)(ws + 171966464);     // 128 KB (2 x 4 x 16 KB)
    int*      ep   = (int*)(ws + 172097536);          // 4 x 128 B epoch lines

    // x fp32 -> f16
    convert_f32_f16<<<16384, 256, 0, stream>>>(x, x16, BATCH * SEQ * IS / 4);
    // weight transposes (fp32 [512][2048] -> f16 [2048][512])
    transpose_w<<<256, 256, 0, stream>>>(wih, wtih);
    transpose_w<<<256, 256, 0, stream>>>(whh, wthh);
    // input projection (writes 128-WG scan layout)
    gemm_xproj<<<4096, 256, 0, stream>>>(x16, wtih, xp);
    // epochs = 0
    hipMemsetAsync(ep, 0, 4096, stream);
    // recurrent scan — 128 single-wave WGs, 4 independent batch-groups
    lstm_scan<<<128, 64, 0, stream>>>(xp, wthh, hb, bias, h0, c0, out, ep);
}